// Round 1
// baseline (331.504 us; speedup 1.0000x reference)
//
#include <hip/hip_runtime.h>
#include <hip/hip_bf16.h>

#define B_  16
#define LQ  2048
#define LS  2048
#define DD  512
#define BQ  128
#define BS  128
#define BK  64
#define NSB (LS / BS)   // 16 s-blocks
#define NKC (DD / BK)   // 8 k-stages

typedef short bf16x8 __attribute__((ext_vector_type(8)));
typedef float f32x4  __attribute__((ext_vector_type(4)));

// async global->LDS, 16B per lane. LDS dest is wave-uniform base + lane*16.
__device__ __forceinline__ void load_lds16(const void* g, void* l) {
  __builtin_amdgcn_global_load_lds((const __attribute__((address_space(1))) void*)g,
                                   (__attribute__((address_space(3))) void*)l,
                                   16, 0, 0);
}

__device__ __forceinline__ unsigned short f2bf(float f) {
  union { float f; unsigned int u; } v; v.f = f;
  unsigned int r = v.u + 0x7fffu + ((v.u >> 16) & 1u);  // RNE
  return (unsigned short)(r >> 16);
}

__global__ __launch_bounds__(256) void cvt_kernel(const float* __restrict__ in,
                                                  unsigned short* __restrict__ out, int n4) {
  int i = blockIdx.x * blockDim.x + threadIdx.x;
  if (i >= n4) return;
  float4 f = ((const float4*)in)[i];
  ushort4 u;
  u.x = f2bf(f.x); u.y = f2bf(f.y); u.z = f2bf(f.z); u.w = f2bf(f.w);
  ((ushort4*)out)[i] = u;
}

// score[b,q] = sum_s softmax(l)[s]*l[s],  l[s] = Q[b,q,:].S[b,s,:]
// MFMA orientation: A = S-tile (M=s), B = Q-tile^T (N=q) -> C[row=s][col=q]
// C layout (16x16x32): col = lane&15, row = (lane>>4)*4 + reg  [m89/m91]
__global__ __launch_bounds__(256) void attn_kernel(const unsigned short* __restrict__ Qw,
                                                   const unsigned short* __restrict__ Sw,
                                                   float* __restrict__ out) {
  __shared__ __align__(16) unsigned short sQ[BQ * BK];  // [row][k], 16 KiB
  __shared__ __align__(16) unsigned short sS[BS * BK];  // [row][k], 16 KiB

  const int qb   = blockIdx.x;
  const int b    = blockIdx.y;
  const int tid  = threadIdx.x;
  const int w    = tid >> 6;      // wave 0..3: q-cols [w*32, w*32+32)
  const int lane = tid & 63;
  const int col  = lane & 15;
  const int quad = lane >> 4;

  const int q0 = qb * BQ;
  const unsigned short* Qb = Qw + (size_t)b * LQ * DD;
  const unsigned short* Sb = Sw + (size_t)b * LS * DD;

  float mstate[2] = { -INFINITY, -INFINITY };
  float se[2]  = { 0.f, 0.f };
  float sel[2] = { 0.f, 0.f };

  f32x4 acc[8][2];   // [s-tile 0..7][q-tile 0..1], 64 VGPRs

  const int rr = lane >> 3;        // staging: row within 8-row group
  const int cc = (lane & 7) * 8;   // staging: k-offset (elements)

  for (int sb = 0; sb < NSB; ++sb) {
    const int s0 = sb * BS;
#pragma unroll
    for (int st = 0; st < 8; ++st)
#pragma unroll
      for (int qt = 0; qt < 2; ++qt)
        acc[st][qt] = (f32x4){0.f, 0.f, 0.f, 0.f};

    for (int kc = 0; kc < NKC; ++kc) {
      __syncthreads();  // previous stage's LDS reads complete
      const int rbase = w * 32;
#pragma unroll
      for (int i = 0; i < 4; ++i) {
        int r = rbase + i * 8 + rr;
        load_lds16(Qb + (size_t)(q0 + r) * DD + kc * BK + cc, &sQ[(rbase + i * 8) * BK]);
      }
#pragma unroll
      for (int i = 0; i < 4; ++i) {
        int r = rbase + i * 8 + rr;
        load_lds16(Sb + (size_t)(s0 + r) * DD + kc * BK + cc, &sS[(rbase + i * 8) * BK]);
      }
      __syncthreads();  // compiler drains vmcnt before s_barrier

#pragma unroll
      for (int kk = 0; kk < 2; ++kk) {
        const int koff = kk * 32 + quad * 8;
        bf16x8 aq[2], asv[8];
#pragma unroll
        for (int qt = 0; qt < 2; ++qt)
          aq[qt] = *(const bf16x8*)&sQ[(w * 32 + qt * 16 + col) * BK + koff];
#pragma unroll
        for (int st = 0; st < 8; ++st)
          asv[st] = *(const bf16x8*)&sS[(st * 16 + col) * BK + koff];
#pragma unroll
        for (int st = 0; st < 8; ++st)
#pragma unroll
          for (int qt = 0; qt < 2; ++qt)
            acc[st][qt] = __builtin_amdgcn_mfma_f32_16x16x32_bf16(asv[st], aq[qt], acc[st][qt], 0, 0, 0);
      }
    }

    // online softmax-weighted-mean update over this 128-s block
#pragma unroll
    for (int qt = 0; qt < 2; ++qt) {
      float lmax = mstate[qt];
#pragma unroll
      for (int st = 0; st < 8; ++st)
#pragma unroll
        for (int r = 0; r < 4; ++r)
          lmax = fmaxf(lmax, acc[st][qt][r]);
      lmax = fmaxf(lmax, __shfl_xor(lmax, 16, 64));
      lmax = fmaxf(lmax, __shfl_xor(lmax, 32, 64));
      float alpha = __expf(mstate[qt] - lmax);  // exp(-inf)=0 on first block
      float pe = 0.f, pel = 0.f;
#pragma unroll
      for (int st = 0; st < 8; ++st)
#pragma unroll
        for (int r = 0; r < 4; ++r) {
          float l = acc[st][qt][r];
          float e = __expf(l - lmax);
          pe += e;
          pel = fmaf(e, l, pel);
        }
      pe  += __shfl_xor(pe, 16, 64);  pe  += __shfl_xor(pe, 32, 64);
      pel += __shfl_xor(pel, 16, 64); pel += __shfl_xor(pel, 32, 64);
      se[qt]  = fmaf(se[qt],  alpha, pe);
      sel[qt] = fmaf(sel[qt], alpha, pel);
      mstate[qt] = lmax;
    }
  }

  if (quad == 0) {
#pragma unroll
    for (int qt = 0; qt < 2; ++qt)
      out[(size_t)b * LQ + q0 + w * 32 + qt * 16 + col] = sel[qt] / se[qt];
  }
}

// fp32 fallback (correctness insurance if ws_size < bf16 scratch need)
__global__ __launch_bounds__(256) void fallback_kernel(const float* __restrict__ Q,
                                                       const float* __restrict__ S,
                                                       float* __restrict__ out) {
  __shared__ float qv[DD];
  __shared__ float red[256];
  const int b = blockIdx.y, qi = blockIdx.x, tid = threadIdx.x;
  const float* qrow = Q + ((size_t)b * LQ + qi) * DD;
  for (int d = tid; d < DD; d += 256) qv[d] = qrow[d];
  __syncthreads();
  const float* Sb = S + (size_t)b * LS * DD;
  float m = -INFINITY, se = 0.f, sel = 0.f;
  for (int s = tid; s < LS; s += 256) {
    const float* srow = Sb + (size_t)s * DD;
    float dot = 0.f;
    for (int d = 0; d < DD; ++d) dot = fmaf(qv[d], srow[d], dot);
    float mn = fmaxf(m, dot);
    float a = __expf(m - mn);
    float e = __expf(dot - mn);
    se  = se * a + e;
    sel = sel * a + e * dot;
    m = mn;
  }
  red[tid] = m; __syncthreads();
  for (int o = 128; o > 0; o >>= 1) { if (tid < o) red[tid] = fmaxf(red[tid], red[tid + o]); __syncthreads(); }
  float M = red[0]; __syncthreads();
  float a = __expf(m - M); se *= a; sel *= a;
  red[tid] = se; __syncthreads();
  for (int o = 128; o > 0; o >>= 1) { if (tid < o) red[tid] += red[tid + o]; __syncthreads(); }
  float SE = red[0]; __syncthreads();
  red[tid] = sel; __syncthreads();
  for (int o = 128; o > 0; o >>= 1) { if (tid < o) red[tid] += red[tid + o]; __syncthreads(); }
  float SEL = red[0];
  if (tid == 0) out[(size_t)b * LQ + qi] = SEL / SE;
}

extern "C" void kernel_launch(void* const* d_in, const int* in_sizes, int n_in,
                              void* d_out, int out_size, void* d_ws, size_t ws_size,
                              hipStream_t stream) {
  const float* Q = (const float*)d_in[0];
  const float* S = (const float*)d_in[1];
  float* out = (float*)d_out;
  const size_t nelem = (size_t)B_ * LQ * DD;           // 16.78M per tensor
  const size_t need  = 2 * nelem * sizeof(unsigned short);  // 67 MiB
  if (ws_size >= need) {
    unsigned short* Qw = (unsigned short*)d_ws;
    unsigned short* Sw = Qw + nelem;
    int n4 = (int)(nelem / 4);
    int blocks = (n4 + 255) / 256;
    cvt_kernel<<<blocks, 256, 0, stream>>>(Q, Qw, n4);
    cvt_kernel<<<blocks, 256, 0, stream>>>(S, Sw, n4);
    attn_kernel<<<dim3(LQ / BQ, B_), 256, 0, stream>>>(Qw, Sw, out);
  } else {
    fallback_kernel<<<dim3(LQ, B_), 256, 0, stream>>>(Q, S, out);
  }
}

// Round 2
// 323.588 us; speedup vs baseline: 1.0245x; 1.0245x over previous
//
#include <hip/hip_runtime.h>
#include <hip/hip_bf16.h>

#define B_  16
#define LQ  2048
#define LS  2048
#define DD  512
#define BQ  128
#define BS  128
#define BK  64
#define NSB (LS / BS)   // 16 s-blocks total
#define NKC (DD / BK)   // 8 k-stages
#define NSPLIT 4

typedef short bf16x8 __attribute__((ext_vector_type(8)));
typedef float f32x4  __attribute__((ext_vector_type(4)));
typedef unsigned short u16x8 __attribute__((ext_vector_type(8)));

// async global->LDS, 16B per lane. LDS dest = wave-uniform base + lane*16.
__device__ __forceinline__ void load_lds16(const void* g, void* l) {
  __builtin_amdgcn_global_load_lds((const __attribute__((address_space(1))) void*)g,
                                   (__attribute__((address_space(3))) void*)l,
                                   16, 0, 0);
}

__device__ __forceinline__ unsigned short f2bf(float f) {
  union { float f; unsigned int u; } v; v.f = f;
  unsigned int r = v.u + 0x7fffu + ((v.u >> 16) & 1u);  // RNE
  return (unsigned short)(r >> 16);
}

// One launch converts both tensors. 8 floats in -> one 16B store.
__global__ __launch_bounds__(256) void cvt_kernel(const float* __restrict__ Q,
                                                  const float* __restrict__ S,
                                                  unsigned short* __restrict__ Qw,
                                                  unsigned short* __restrict__ Sw, int n8) {
  int i = blockIdx.x * blockDim.x + threadIdx.x;
  const float* src; unsigned short* dst; int j;
  if (i < n8)            { src = Q; dst = Qw; j = i; }
  else if (i < 2 * n8)   { src = S; dst = Sw; j = i - n8; }
  else return;
  float4 f0 = ((const float4*)src)[j * 2];
  float4 f1 = ((const float4*)src)[j * 2 + 1];
  u16x8 u;
  u[0] = f2bf(f0.x); u[1] = f2bf(f0.y); u[2] = f2bf(f0.z); u[3] = f2bf(f0.w);
  u[4] = f2bf(f1.x); u[5] = f2bf(f1.y); u[6] = f2bf(f1.z); u[7] = f2bf(f1.w);
  ((u16x8*)dst)[j] = u;
}

// score[b,q] = sum_s softmax(l)[s]*l[s],  l[s] = Q[b,q,:].S[b,s,:]
// MFMA: A = S-tile (M=s), B = Q-tile^T (N=q) -> C[row=s][col=q]
// C layout (16x16x32): col = lane&15, row = (lane>>4)*4 + reg  [m89/m91]
// LDS k-chunk XOR swizzle: LDS[row][j] holds global chunk (j ^ (row&7));
// read chunk c at j = c ^ (row&7). Breaks the quad*4 bank fixation -> 2-way.
__global__ __launch_bounds__(256) void attn_kernel(const unsigned short* __restrict__ Qw,
                                                   const unsigned short* __restrict__ Sw,
                                                   float* __restrict__ out,
                                                   float* __restrict__ pm,
                                                   float* __restrict__ pse,
                                                   float* __restrict__ psel,
                                                   int nsplit) {
  __shared__ __align__(16) unsigned short sQ[BQ * BK];  // 16 KiB
  __shared__ __align__(16) unsigned short sS[BS * BK];  // 16 KiB

  const int qb   = blockIdx.x;
  const int b    = blockIdx.y;
  const int spl  = blockIdx.z;
  const int tid  = threadIdx.x;
  const int w    = tid >> 6;      // wave 0..3: q-cols [w*32, w*32+32)
  const int lane = tid & 63;
  const int col  = lane & 15;
  const int quad = lane >> 4;
  const int c7   = col & 7;

  const int q0 = qb * BQ;
  const unsigned short* Qb = Qw + (size_t)b * LQ * DD;
  const unsigned short* Sb = Sw + (size_t)b * LS * DD;

  float mstate[2] = { -INFINITY, -INFINITY };
  float se[2]  = { 0.f, 0.f };
  float sel[2] = { 0.f, 0.f };

  f32x4 acc[8][2];   // [s-tile][q-tile]

  const int rr = lane >> 3;                    // row within 8-row staging group
  const int cc = ((lane & 7) ^ rr) * 8;        // swizzled global k-chunk

  const int sbs = spl * (NSB / nsplit);
  const int sbe = sbs + (NSB / nsplit);

  for (int sb = sbs; sb < sbe; ++sb) {
    const int s0 = sb * BS;
#pragma unroll
    for (int st = 0; st < 8; ++st)
#pragma unroll
      for (int qt = 0; qt < 2; ++qt)
        acc[st][qt] = (f32x4){0.f, 0.f, 0.f, 0.f};

    for (int kc = 0; kc < NKC; ++kc) {
      __syncthreads();  // previous stage's LDS reads complete
      const int rbase = w * 32;
#pragma unroll
      for (int i = 0; i < 4; ++i) {
        int r = rbase + i * 8 + rr;
        load_lds16(Qb + (size_t)(q0 + r) * DD + kc * BK + cc, &sQ[(rbase + i * 8) * BK]);
      }
#pragma unroll
      for (int i = 0; i < 4; ++i) {
        int r = rbase + i * 8 + rr;
        load_lds16(Sb + (size_t)(s0 + r) * DD + kc * BK + cc, &sS[(rbase + i * 8) * BK]);
      }
      __syncthreads();  // drains vmcnt before barrier

#pragma unroll
      for (int kk = 0; kk < 2; ++kk) {
        bf16x8 aq[2], asv[8];
#pragma unroll
        for (int qt = 0; qt < 2; ++qt) {
          const int koff = (((kk * 4 + quad) ^ c7)) * 8;
          aq[qt] = *(const bf16x8*)&sQ[(w * 32 + qt * 16 + col) * BK + koff];
        }
#pragma unroll
        for (int st = 0; st < 8; ++st) {
          const int koff = (((kk * 4 + quad) ^ c7)) * 8;
          asv[st] = *(const bf16x8*)&sS[(st * 16 + col) * BK + koff];
        }
#pragma unroll
        for (int st = 0; st < 8; ++st)
#pragma unroll
          for (int qt = 0; qt < 2; ++qt)
            acc[st][qt] = __builtin_amdgcn_mfma_f32_16x16x32_bf16(asv[st], aq[qt], acc[st][qt], 0, 0, 0);
      }
    }

    // online softmax-weighted-mean update over this 128-s block
#pragma unroll
    for (int qt = 0; qt < 2; ++qt) {
      float lmax = mstate[qt];
#pragma unroll
      for (int st = 0; st < 8; ++st)
#pragma unroll
        for (int r = 0; r < 4; ++r)
          lmax = fmaxf(lmax, acc[st][qt][r]);
      lmax = fmaxf(lmax, __shfl_xor(lmax, 16, 64));
      lmax = fmaxf(lmax, __shfl_xor(lmax, 32, 64));
      float alpha = __expf(mstate[qt] - lmax);  // exp(-inf)=0 on first block
      float pe = 0.f, pel = 0.f;
#pragma unroll
      for (int st = 0; st < 8; ++st)
#pragma unroll
        for (int r = 0; r < 4; ++r) {
          float l = acc[st][qt][r];
          float e = __expf(l - lmax);
          pe += e;
          pel = fmaf(e, l, pel);
        }
      pe  += __shfl_xor(pe, 16, 64);  pe  += __shfl_xor(pe, 32, 64);
      pel += __shfl_xor(pel, 16, 64); pel += __shfl_xor(pel, 32, 64);
      se[qt]  = fmaf(se[qt],  alpha, pe);
      sel[qt] = fmaf(sel[qt], alpha, pel);
      mstate[qt] = lmax;
    }
  }

  if (quad == 0) {
#pragma unroll
    for (int qt = 0; qt < 2; ++qt) {
      const size_t qi = (size_t)b * LQ + q0 + w * 32 + qt * 16 + col;
      if (nsplit == 1) {
        out[qi] = sel[qt] / se[qt];
      } else {
        pm[qi * NSPLIT + spl]   = mstate[qt];
        pse[qi * NSPLIT + spl]  = se[qt];
        psel[qi * NSPLIT + spl] = sel[qt];
      }
    }
  }
}

__global__ __launch_bounds__(256) void combine_kernel(const float* __restrict__ pm,
                                                      const float* __restrict__ pse,
                                                      const float* __restrict__ psel,
                                                      float* __restrict__ out) {
  int i = blockIdx.x * blockDim.x + threadIdx.x;
  if (i >= B_ * LQ) return;
  float M = -INFINITY;
#pragma unroll
  for (int s = 0; s < NSPLIT; ++s) M = fmaxf(M, pm[i * NSPLIT + s]);
  float SE = 0.f, SEL = 0.f;
#pragma unroll
  for (int s = 0; s < NSPLIT; ++s) {
    float a = __expf(pm[i * NSPLIT + s] - M);
    SE  = fmaf(pse[i * NSPLIT + s],  a, SE);
    SEL = fmaf(psel[i * NSPLIT + s], a, SEL);
  }
  out[i] = SEL / SE;
}

// fp32 fallback (correctness insurance if ws too small)
__global__ __launch_bounds__(256) void fallback_kernel(const float* __restrict__ Q,
                                                       const float* __restrict__ S,
                                                       float* __restrict__ out) {
  __shared__ float qv[DD];
  __shared__ float red[256];
  const int b = blockIdx.y, qi = blockIdx.x, tid = threadIdx.x;
  const float* qrow = Q + ((size_t)b * LQ + qi) * DD;
  for (int d = tid; d < DD; d += 256) qv[d] = qrow[d];
  __syncthreads();
  const float* Sb = S + (size_t)b * LS * DD;
  float m = -INFINITY, se = 0.f, sel = 0.f;
  for (int s = tid; s < LS; s += 256) {
    const float* srow = Sb + (size_t)s * DD;
    float dot = 0.f;
    for (int d = 0; d < DD; ++d) dot = fmaf(qv[d], srow[d], dot);
    float mn = fmaxf(m, dot);
    float a = __expf(m - mn);
    float e = __expf(dot - mn);
    se  = se * a + e;
    sel = sel * a + e * dot;
    m = mn;
  }
  red[tid] = m; __syncthreads();
  for (int o = 128; o > 0; o >>= 1) { if (tid < o) red[tid] = fmaxf(red[tid], red[tid + o]); __syncthreads(); }
  float M = red[0]; __syncthreads();
  float a = __expf(m - M); se *= a; sel *= a;
  red[tid] = se; __syncthreads();
  for (int o = 128; o > 0; o >>= 1) { if (tid < o) red[tid] += red[tid + o]; __syncthreads(); }
  float SE = red[0]; __syncthreads();
  red[tid] = sel; __syncthreads();
  for (int o = 128; o > 0; o >>= 1) { if (tid < o) red[tid] += red[tid + o]; __syncthreads(); }
  float SEL = red[0];
  if (tid == 0) out[(size_t)b * LQ + qi] = SEL / SE;
}

extern "C" void kernel_launch(void* const* d_in, const int* in_sizes, int n_in,
                              void* d_out, int out_size, void* d_ws, size_t ws_size,
                              hipStream_t stream) {
  const float* Q = (const float*)d_in[0];
  const float* S = (const float*)d_in[1];
  float* out = (float*)d_out;
  const size_t nelem = (size_t)B_ * LQ * DD;                    // 16.78M / tensor
  const size_t need_base  = 2 * nelem * sizeof(unsigned short); // 67 MiB
  const size_t part_elems = (size_t)B_ * LQ * NSPLIT;
  const size_t need_split = need_base + 3 * part_elems * sizeof(float);

  if (ws_size >= need_base) {
    unsigned short* Qw = (unsigned short*)d_ws;
    unsigned short* Sw = Qw + nelem;
    int n8 = (int)(nelem / 8);
    cvt_kernel<<<(2 * n8 + 255) / 256, 256, 0, stream>>>(Q, S, Qw, Sw, n8);
    if (ws_size >= need_split) {
      float* pm   = (float*)(Sw + nelem);
      float* pse  = pm + part_elems;
      float* psel = pse + part_elems;
      attn_kernel<<<dim3(LQ / BQ, B_, NSPLIT), 256, 0, stream>>>(Qw, Sw, out, pm, pse, psel, NSPLIT);
      combine_kernel<<<(B_ * LQ + 255) / 256, 256, 0, stream>>>(pm, pse, psel, out);
    } else {
      attn_kernel<<<dim3(LQ / BQ, B_, 1), 256, 0, stream>>>(Qw, Sw, out, nullptr, nullptr, nullptr, 1);
    }
  } else {
    fallback_kernel<<<dim3(LQ, B_), 256, 0, stream>>>(Q, S, out);
  }
}

// Round 3
// 231.228 us; speedup vs baseline: 1.4337x; 1.3994x over previous
//
#include <hip/hip_runtime.h>
#include <hip/hip_bf16.h>

#define B_  16
#define LQ  2048
#define LS  2048
#define DD  512
#define BQ  128
#define BS  128
#define BK  64
#define NSB (LS / BS)   // 16 s-blocks total
#define NKC (DD / BK)   // 8 k-stages
#define NSPLIT 4

typedef short bf16x8 __attribute__((ext_vector_type(8)));
typedef float f32x4  __attribute__((ext_vector_type(4)));

// async global->LDS, 16B per lane. LDS dest = wave-uniform base + lane*16.
__device__ __forceinline__ void load_lds16(const void* g, void* l) {
  __builtin_amdgcn_global_load_lds((const __attribute__((address_space(1))) void*)g,
                                   (__attribute__((address_space(3))) void*)l,
                                   16, 0, 0);
}

__device__ __forceinline__ unsigned short f2bf(float f) {
  union { float f; unsigned int u; } v; v.f = f;
  unsigned int r = v.u + 0x7fffu + ((v.u >> 16) & 1u);  // RNE
  return (unsigned short)(r >> 16);
}

// Exact-size grid: blocks [0, nblk) convert Q, [nblk, 2nblk) convert S.
// Lane reads 16B contiguous, writes 8B contiguous.
__global__ __launch_bounds__(256) void cvt_kernel(const float* __restrict__ Q,
                                                  const float* __restrict__ S,
                                                  unsigned short* __restrict__ Qw,
                                                  unsigned short* __restrict__ Sw,
                                                  int nblk) {
  int blk = blockIdx.x;
  const float* src; unsigned short* dst;
  if (blk < nblk) { src = Q; dst = Qw; } else { src = S; dst = Sw; blk -= nblk; }
  int i = blk * 256 + threadIdx.x;   // float4 index
  float4 f = ((const float4*)src)[i];
  ushort4 u;
  u.x = f2bf(f.x); u.y = f2bf(f.y); u.z = f2bf(f.z); u.w = f2bf(f.w);
  ((ushort4*)dst)[i] = u;
}

// score[b,q] = sum_s softmax(l)[s]*l[s],  l[s] = Q[b,q,:].S[b,s,:]
// MFMA: A = S-tile (M=s), B = Q-tile^T (N=q) -> C[row=s][col=q]
// C layout (16x16x32): col = lane&15, row = (lane>>4)*4 + reg  [m89/m91]
// 512 threads = 8 waves: wave w -> s-half h=w&1 (64 rows), q-group g=w>>2... g=w>>1 (32 cols).
// 2 waves/SIMD minimum from a single resident block (the round-2 lesson: don't
// depend on multi-block residency for latency hiding).
// LDS k-chunk XOR swizzle (round 2, conflict-free): LDS[row][j] holds global
// chunk j^(row&7); read chunk c at j = c^(row&7).
__global__ __launch_bounds__(512, 4) void attn_kernel(const unsigned short* __restrict__ Qw,
                                                      const unsigned short* __restrict__ Sw,
                                                      float* __restrict__ out,
                                                      float* __restrict__ pm,
                                                      float* __restrict__ pse,
                                                      float* __restrict__ psel,
                                                      int nsplit) {
  __shared__ __align__(16) unsigned short sQ[BQ * BK];  // 16 KiB
  __shared__ __align__(16) unsigned short sS[BS * BK];  // 16 KiB

  const int qb   = blockIdx.x;
  const int b    = blockIdx.y;
  const int spl  = blockIdx.z;
  const int tid  = threadIdx.x;
  const int w    = tid >> 6;      // 0..7
  const int lane = tid & 63;
  const int h    = w & 1;         // s-half: rows [h*64, h*64+64)
  const int g    = w >> 1;        // q-group: cols [g*32, g*32+32)
  const int col  = lane & 15;
  const int quad = lane >> 4;
  const int c7   = col & 7;

  const int q0 = qb * BQ;
  const unsigned short* Qb = Qw + (size_t)b * LQ * DD;
  const unsigned short* Sb = Sw + (size_t)b * LS * DD;

  float mst[2] = { -INFINITY, -INFINITY };
  float se[2]  = { 0.f, 0.f };
  float sel[2] = { 0.f, 0.f };

  f32x4 acc[4][2];   // [s-tile within half][q-tile] = 32 VGPRs

  const int rr    = lane >> 3;                 // row within 8-row staging group
  const int cc    = ((lane & 7) ^ rr) * 8;     // swizzled global k-chunk
  const int srow0 = (w & 3) * 32;              // staging row base (waves 0-3: sQ, 4-7: sS)

  const int sbs = spl * (NSB / nsplit);
  const int sbe = sbs + (NSB / nsplit);

  for (int sb = sbs; sb < sbe; ++sb) {
    const int s0 = sb * BS;
#pragma unroll
    for (int st = 0; st < 4; ++st)
#pragma unroll
      for (int qt = 0; qt < 2; ++qt)
        acc[st][qt] = (f32x4){0.f, 0.f, 0.f, 0.f};

    for (int kc = 0; kc < NKC; ++kc) {
      __syncthreads();  // previous stage's LDS reads complete
      if (w < 4) {
#pragma unroll
        for (int i = 0; i < 4; ++i) {
          int r = srow0 + i * 8 + rr;
          load_lds16(Qb + (size_t)(q0 + r) * DD + kc * BK + cc, &sQ[(srow0 + i * 8) * BK]);
        }
      } else {
#pragma unroll
        for (int i = 0; i < 4; ++i) {
          int r = srow0 + i * 8 + rr;
          load_lds16(Sb + (size_t)(s0 + r) * DD + kc * BK + cc, &sS[(srow0 + i * 8) * BK]);
        }
      }
      __syncthreads();  // drains vmcnt before barrier

#pragma unroll
      for (int kk = 0; kk < 2; ++kk) {
        const int koff = ((kk * 4 + quad) ^ c7) * 8;
        bf16x8 aq[2], asv[4];
#pragma unroll
        for (int qt = 0; qt < 2; ++qt)
          aq[qt] = *(const bf16x8*)&sQ[(g * 32 + qt * 16 + col) * BK + koff];
#pragma unroll
        for (int st = 0; st < 4; ++st)
          asv[st] = *(const bf16x8*)&sS[(h * 64 + st * 16 + col) * BK + koff];
#pragma unroll
        for (int st = 0; st < 4; ++st)
#pragma unroll
          for (int qt = 0; qt < 2; ++qt)
            acc[st][qt] = __builtin_amdgcn_mfma_f32_16x16x32_bf16(asv[st], aq[qt], acc[st][qt], 0, 0, 0);
      }
    }

    // online softmax-weighted-mean update over this wave's 64-s half-block
#pragma unroll
    for (int qt = 0; qt < 2; ++qt) {
      float lmax = mst[qt];
#pragma unroll
      for (int st = 0; st < 4; ++st)
#pragma unroll
        for (int r = 0; r < 4; ++r)
          lmax = fmaxf(lmax, acc[st][qt][r]);
      lmax = fmaxf(lmax, __shfl_xor(lmax, 16, 64));
      lmax = fmaxf(lmax, __shfl_xor(lmax, 32, 64));
      float alpha = __expf(mst[qt] - lmax);  // exp(-inf)=0 on first block
      float pe = 0.f, pel = 0.f;
#pragma unroll
      for (int st = 0; st < 4; ++st)
#pragma unroll
        for (int r = 0; r < 4; ++r) {
          float l = acc[st][qt][r];
          float e = __expf(l - lmax);
          pe += e;
          pel = fmaf(e, l, pel);
        }
      pe  += __shfl_xor(pe, 16, 64);  pe  += __shfl_xor(pe, 32, 64);
      pel += __shfl_xor(pel, 16, 64); pel += __shfl_xor(pel, 32, 64);
      se[qt]  = fmaf(se[qt],  alpha, pe);
      sel[qt] = fmaf(sel[qt], alpha, pel);
      mst[qt] = lmax;
    }
  }

  // merge the two s-halves (h=0,1) per q-group via LDS, then write
  __syncthreads();
  float* red = (float*)sQ;   // 3*256 floats = 3 KiB, sQ no longer needed
  if (quad == 0) {
#pragma unroll
    for (int qt = 0; qt < 2; ++qt) {
      int idx = ((g * 2 + h) * 2 + qt) * 16 + col;
      red[idx]       = mst[qt];
      red[256 + idx] = se[qt];
      red[512 + idx] = sel[qt];
    }
  }
  __syncthreads();
  if (h == 0 && quad == 0) {
#pragma unroll
    for (int qt = 0; qt < 2; ++qt) {
      int i0 = ((g * 2 + 0) * 2 + qt) * 16 + col;
      int i1 = ((g * 2 + 1) * 2 + qt) * 16 + col;
      float m0 = red[i0], m1 = red[i1];
      float M  = fmaxf(m0, m1);
      float a0 = __expf(m0 - M), a1 = __expf(m1 - M);
      float SE  = red[256 + i0] * a0 + red[256 + i1] * a1;
      float SEL = red[512 + i0] * a0 + red[512 + i1] * a1;
      size_t qi = (size_t)b * LQ + q0 + g * 32 + qt * 16 + col;
      if (nsplit == 1) {
        out[qi] = SEL / SE;
      } else {
        pm[qi * NSPLIT + spl]   = M;
        pse[qi * NSPLIT + spl]  = SE;
        psel[qi * NSPLIT + spl] = SEL;
      }
    }
  }
}

__global__ __launch_bounds__(256) void combine_kernel(const float* __restrict__ pm,
                                                      const float* __restrict__ pse,
                                                      const float* __restrict__ psel,
                                                      float* __restrict__ out) {
  int i = blockIdx.x * blockDim.x + threadIdx.x;
  if (i >= B_ * LQ) return;
  float M = -INFINITY;
#pragma unroll
  for (int s = 0; s < NSPLIT; ++s) M = fmaxf(M, pm[i * NSPLIT + s]);
  float SE = 0.f, SEL = 0.f;
#pragma unroll
  for (int s = 0; s < NSPLIT; ++s) {
    float a = __expf(pm[i * NSPLIT + s] - M);
    SE  = fmaf(pse[i * NSPLIT + s],  a, SE);
    SEL = fmaf(psel[i * NSPLIT + s], a, SEL);
  }
  out[i] = SEL / SE;
}

// fp32 fallback (correctness insurance if ws too small)
__global__ __launch_bounds__(256) void fallback_kernel(const float* __restrict__ Q,
                                                       const float* __restrict__ S,
                                                       float* __restrict__ out) {
  __shared__ float qv[DD];
  __shared__ float red[256];
  const int b = blockIdx.y, qi = blockIdx.x, tid = threadIdx.x;
  const float* qrow = Q + ((size_t)b * LQ + qi) * DD;
  for (int d = tid; d < DD; d += 256) qv[d] = qrow[d];
  __syncthreads();
  const float* Sb = S + (size_t)b * LS * DD;
  float m = -INFINITY, se = 0.f, sel = 0.f;
  for (int s = tid; s < LS; s += 256) {
    const float* srow = Sb + (size_t)s * DD;
    float dot = 0.f;
    for (int d = 0; d < DD; ++d) dot = fmaf(qv[d], srow[d], dot);
    float mn = fmaxf(m, dot);
    float a = __expf(m - mn);
    float e = __expf(dot - mn);
    se  = se * a + e;
    sel = sel * a + e * dot;
    m = mn;
  }
  red[tid] = m; __syncthreads();
  for (int o = 128; o > 0; o >>= 1) { if (tid < o) red[tid] = fmaxf(red[tid], red[tid + o]); __syncthreads(); }
  float M = red[0]; __syncthreads();
  float a = __expf(m - M); se *= a; sel *= a;
  red[tid] = se; __syncthreads();
  for (int o = 128; o > 0; o >>= 1) { if (tid < o) red[tid] += red[tid + o]; __syncthreads(); }
  float SE = red[0]; __syncthreads();
  red[tid] = sel; __syncthreads();
  for (int o = 128; o > 0; o >>= 1) { if (tid < o) red[tid] += red[tid + o]; __syncthreads(); }
  float SEL = red[0];
  if (tid == 0) out[(size_t)b * LQ + qi] = SEL / SE;
}

extern "C" void kernel_launch(void* const* d_in, const int* in_sizes, int n_in,
                              void* d_out, int out_size, void* d_ws, size_t ws_size,
                              hipStream_t stream) {
  const float* Q = (const float*)d_in[0];
  const float* S = (const float*)d_in[1];
  float* out = (float*)d_out;
  const size_t nelem = (size_t)B_ * LQ * DD;                    // 16.78M / tensor
  const size_t need_base  = 2 * nelem * sizeof(unsigned short); // 67 MiB
  const size_t part_elems = (size_t)B_ * LQ * NSPLIT;
  const size_t need_split = need_base + 3 * part_elems * sizeof(float);

  if (ws_size >= need_base) {
    unsigned short* Qw = (unsigned short*)d_ws;
    unsigned short* Sw = Qw + nelem;
    int nblk = (int)(nelem / 4 / 256);   // exact: nelem divisible by 1024
    cvt_kernel<<<2 * nblk, 256, 0, stream>>>(Q, S, Qw, Sw, nblk);
    if (ws_size >= need_split) {
      float* pm   = (float*)(Sw + nelem);
      float* pse  = pm + part_elems;
      float* psel = pse + part_elems;
      attn_kernel<<<dim3(LQ / BQ, B_, NSPLIT), 512, 0, stream>>>(Qw, Sw, out, pm, pse, psel, NSPLIT);
      combine_kernel<<<(B_ * LQ + 255) / 256, 256, 0, stream>>>(pm, pse, psel, out);
    } else {
      attn_kernel<<<dim3(LQ / BQ, B_, 1), 512, 0, stream>>>(Qw, Sw, out, nullptr, nullptr, nullptr, 1);
    }
  } else {
    fallback_kernel<<<dim3(LQ, B_), 256, 0, stream>>>(Q, S, out);
  }
}